// Round 9
// baseline (434.474 us; speedup 1.0000x reference)
//
#include <hip/hip_runtime.h>

#define HIDDEN 64
#define IN_DIM 512
#define CAP 4096      // bucket capacity (mean load ~2046 for E=1.6M over 782 buckets; 45 sigma headroom)
#define NB_MAX 1024   // max buckets (n_nodes <= 131072)
#define DBINS 512     // degree-sort bins (chunk count = ceil(deg/16) <= 256)

typedef short v8s __attribute__((ext_vector_type(8)));
typedef float v4f __attribute__((ext_vector_type(4)));

static __device__ __forceinline__ unsigned short f2bf(float f) {
    unsigned int u = __float_as_uint(f);
    u = (u + 0x7FFF + ((u >> 16) & 1)) >> 16;   // RNE
    return (unsigned short)u;
}
static __device__ __forceinline__ float bf2f(unsigned short u) {
    return __uint_as_float(((unsigned int)u) << 16);
}
static __device__ __forceinline__ float bflo(unsigned u) { return __uint_as_float(u << 16); }
static __device__ __forceinline__ float bfhi(unsigned u) { return __uint_as_float(u & 0xffff0000u); }

// ---------------- init: zero cursors + pool accumulators + sentinel rows ---
__global__ void k_init(int* cursor, float* gsum, int* gcnt,
                       unsigned short* bufA, unsigned short* bufB, int* ghist, int n_nodes) {
    int i = blockIdx.x * 256 + threadIdx.x;
    if (i < NB_MAX) cursor[i] = 0;
    if (i < 256) { gsum[i] = 0.f; gcnt[i] = 0; }
    if (i < DBINS) ghist[i] = 0;
    if (i < 64) {
        bufA[(size_t)n_nodes * 64 + i] = 0;
        bufB[(size_t)n_nodes * 64 + i] = 0;
    }
}

// ---------------- bin edges by dst>>7 into fixed-stride buckets ------------
__launch_bounds__(256)
__global__ void k_bin(const int* __restrict__ src, const int* __restrict__ dst,
                      int* cursor, unsigned* __restrict__ bucket_data, int n_edges) {
    __shared__ unsigned words[4096];          // 16 KB
    __shared__ unsigned short binsh[4096];    // 8 KB
    __shared__ int hist[NB_MAX];              // 4 KB
    __shared__ int base[NB_MAX];              // 4 KB
    const int tid = threadIdx.x;
    const int e0 = blockIdx.x * 4096;
    for (int i = tid; i < NB_MAX; i += 256) hist[i] = 0;
    __syncthreads();
    for (int i = tid; i < 4096; i += 256) {
        int e = e0 + i;
        if (e < n_edges) {
            int d = dst[e], s = src[e];
            words[i] = ((unsigned)s << 7) | (unsigned)(d & 127);
            int b = d >> 7;
            binsh[i] = (unsigned short)b;
            atomicAdd(&hist[b], 1);
        } else binsh[i] = 0xFFFFu;
    }
    __syncthreads();
    for (int b = tid; b < NB_MAX; b += 256) {
        int c = hist[b];
        base[b] = c ? atomicAdd(&cursor[b], c) : 0;
        hist[b] = 0;
    }
    __syncthreads();
    for (int i = tid; i < 4096; i += 256) {
        unsigned short b = binsh[i];
        if (b != 0xFFFFu) {
            int slot = atomicAdd(&hist[b], 1);
            int p = base[b] + slot;
            if (p < CAP) bucket_data[(size_t)b * CAP + p] = words[i];
        }
    }
}

// ---------------- exclusive scan of bucket counts -> bucket_base -----------
__launch_bounds__(256)
__global__ void k_bexc(const int* __restrict__ cursor, int* __restrict__ bucket_base,
                       int* __restrict__ row_start, int n_nodes, int nbuck) {
    __shared__ int wsum[4];
    const int t = threadIdx.x, lane = t & 63, w = t >> 6;
    int v[4], s = 0;
#pragma unroll
    for (int k = 0; k < 4; ++k) {
        int i = t * 4 + k;
        int c = (i < nbuck) ? cursor[i] : 0;
        if (c > CAP) c = CAP;
        v[k] = s; s += c;
    }
    int inc = s;
#pragma unroll
    for (int off = 1; off < 64; off <<= 1) {
        int u = __shfl_up(inc, off, 64);
        if (lane >= off) inc += u;
    }
    if (lane == 63) wsum[w] = inc;
    __syncthreads();
    int cross = 0;
    for (int i = 0; i < w; ++i) cross += wsum[i];
    int b0 = cross + inc - s;
#pragma unroll
    for (int k = 0; k < 4; ++k) {
        int i = t * 4 + k;
        if (i < NB_MAX) bucket_base[i] = b0 + v[k];
    }
    if (t == 255) row_start[n_nodes] = cross + inc;   // total kept edges
}

// ---------------- per-bucket CSR build (coalesced, local LDS) --------------
// csr entries are PRE-SCALED byte offsets (src*128). Also feeds the global
// chunk-count histogram (ghist) for the degree sort.
__launch_bounds__(256)
__global__ void k_csr(const unsigned* __restrict__ bucket_data, const int* __restrict__ cursor,
                      const int* __restrict__ bucket_base,
                      int* __restrict__ row_start, int* __restrict__ csr,
                      float* __restrict__ dinv, int* __restrict__ ghist, int n_nodes) {
    __shared__ unsigned words[CAP];   // 16 KB
    __shared__ int cnt[128];
    __shared__ int loff[128];
    __shared__ int cur[128];
    __shared__ int dhist[DBINS];      // 2 KB
    __shared__ int w0sum;
    const int tid = threadIdx.x, bin = blockIdx.x, n0 = bin << 7;
    int c = cursor[bin]; if (c > CAP) c = CAP;
    const unsigned* bd = bucket_data + (size_t)bin * CAP;
    for (int i = tid; i < c; i += 256) words[i] = bd[i];
    if (tid < 128) { cnt[tid] = 0; cur[tid] = 0; }
    for (int i = tid; i < DBINS; i += 256) dhist[i] = 0;
    __syncthreads();
    for (int i = tid; i < c; i += 256) atomicAdd(&cnt[words[i] & 127], 1);
    __syncthreads();
    int val = 0, inc = 0;
    if (tid < 128) {
        const int lane = tid & 63;
        val = cnt[tid];
        inc = val;
#pragma unroll
        for (int off = 1; off < 64; off <<= 1) {
            int u = __shfl_up(inc, off, 64);
            if (lane >= off) inc += u;
        }
        if (tid == 63) w0sum = inc;
    }
    __syncthreads();
    if (tid < 128) {
        int excl = inc - val + ((tid >= 64) ? w0sum : 0);
        loff[tid] = excl;
        int n = n0 + tid;
        if (n < n_nodes) {
            row_start[n] = bucket_base[bin] + excl;
            dinv[n] = rsqrtf((float)(val + 1));   // +1 self loop
            int cb = (val + 15) >> 4;             // chunk count, <= 256
            atomicAdd(&dhist[cb], 1);
        }
    }
    __syncthreads();
    for (int b = tid; b < DBINS; b += 256)
        if (dhist[b]) atomicAdd(&ghist[b], dhist[b]);
    const int gbase = bucket_base[bin];
    for (int i = tid; i < c; i += 256) {
        unsigned wd = words[i];
        int d = wd & 127;
        int slot = atomicAdd(&cur[d], 1);
        csr[gbase + loff[d] + slot] = (int)(wd & 0xFFFFFF80u);  // src*128 byte offset
    }
}

// ---------------- exclusive scan of chunk-count histogram -> dcur ----------
__launch_bounds__(256)
__global__ void k_cscan(const int* __restrict__ ghist, int* __restrict__ dcur) {
    __shared__ int wsum[4];
    const int t = threadIdx.x, lane = t & 63, w = t >> 6;
    int v0 = ghist[2 * t], v1 = ghist[2 * t + 1];
    int s = v0 + v1;
    int inc = s;
#pragma unroll
    for (int off = 1; off < 64; off <<= 1) {
        int u = __shfl_up(inc, off, 64);
        if (lane >= off) inc += u;
    }
    if (lane == 63) wsum[w] = inc;
    __syncthreads();
    int cross = 0;
    for (int i = 0; i < w; ++i) cross += wsum[i];
    int b0 = cross + inc - s;
    dcur[2 * t] = b0;
    dcur[2 * t + 1] = b0 + v0;
}

// ---------------- place nodes into perm, grouped by chunk count ------------
__launch_bounds__(256)
__global__ void k_cplace(const int* __restrict__ row_start, int* dcur,
                         int* __restrict__ perm, int n_nodes) {
    __shared__ int lh[DBINS];
    __shared__ int lbase[DBINS];
    __shared__ int lcur[DBINS];
    const int tid = threadIdx.x;
    const int n0 = blockIdx.x * 4096;
    for (int i = tid; i < DBINS; i += 256) lh[i] = 0;
    __syncthreads();
    for (int i = tid; i < 4096; i += 256) {
        int n = n0 + i;
        if (n < n_nodes) {
            int deg = row_start[n + 1] - row_start[n];
            atomicAdd(&lh[(deg + 15) >> 4], 1);
        }
    }
    __syncthreads();
    for (int b = tid; b < DBINS; b += 256) {
        int cnt = lh[b];
        lbase[b] = cnt ? atomicAdd(&dcur[b], cnt) : 0;
        lcur[b] = 0;
    }
    __syncthreads();
    for (int i = tid; i < 4096; i += 256) {
        int n = n0 + i;
        if (n < n_nodes) {
            int deg = row_start[n + 1] - row_start[n];
            int cb = (deg + 15) >> 4;
            int slot = atomicAdd(&lcur[cb], 1);
            perm[lbase[cb] + slot] = n;
        }
    }
}

// ---------------- W1,W2 -> bf16 transposed Wt [64][512], Wt2 [64][64] ------
__global__ void k_prep(const float* __restrict__ W1, const float* __restrict__ W2,
                       unsigned short* __restrict__ Wt, unsigned short* __restrict__ Wt2) {
    int idx = blockIdx.x * 256 + threadIdx.x;
    if (idx < HIDDEN * IN_DIM) {
        int n = idx >> 9, k = idx & 511;
        Wt[(size_t)n * 512 + k] = f2bf(W1[(size_t)k * 64 + n]);
    } else {
        int j = idx - HIDDEN * IN_DIM;   // 0..4095
        int n = j >> 6, k = j & 63;
        Wt2[(size_t)n * 64 + k] = f2bf(W2[(size_t)k * 64 + n]);
    }
}

// ---------------- GEMM1 (MFMA bf16): s1 = bf16(dinv .* (x @ W1)) -----------
__launch_bounds__(256)
__global__ void k_gemm1m(const float* __restrict__ x, const unsigned short* __restrict__ Wt,
                         const float* __restrict__ dinv, unsigned short* __restrict__ s1,
                         int n_nodes) {
    __shared__ __align__(16) unsigned short lX[64 * 136];
    __shared__ __align__(16) unsigned short lW[64 * 136];
    const int tid  = threadIdx.x;
    const int lane = tid & 63;
    const int w    = tid >> 6;
    const int quad = lane >> 4;
    const int m16  = lane & 15;
    const int row0 = blockIdx.x * 64;

    v4f acc[4];
#pragma unroll
    for (int b = 0; b < 4; ++b) acc[b] = (v4f){0.f, 0.f, 0.f, 0.f};

    for (int kc = 0; kc < IN_DIM; kc += 128) {
        __syncthreads();
#pragma unroll
        for (int i = 0; i < 8; ++i) {
            int fidx = tid + i * 256;
            int r  = fidx >> 5;
            int c4 = fidx & 31;
            int gr = row0 + r;
            float4 v = make_float4(0.f, 0.f, 0.f, 0.f);
            if (gr < n_nodes) v = ((const float4*)(x + (size_t)gr * IN_DIM + kc))[c4];
            ushort4 u = make_ushort4(f2bf(v.x), f2bf(v.y), f2bf(v.z), f2bf(v.w));
            *(ushort4*)(lX + r * 136 + c4 * 4) = u;
        }
#pragma unroll
        for (int i = 0; i < 4; ++i) {
            int idx = tid + i * 256;
            int n  = idx >> 4;
            int c8 = idx & 15;
            uint4 u = *(const uint4*)(Wt + (size_t)n * 512 + kc + c8 * 8);
            *(uint4*)(lW + n * 136 + c8 * 8) = u;
        }
        __syncthreads();
#pragma unroll
        for (int kk = 0; kk < 128; kk += 32) {
            v8s a = *(const v8s*)(lX + (w * 16 + m16) * 136 + kk + quad * 8);
#pragma unroll
            for (int b = 0; b < 4; ++b) {
                v8s bb = *(const v8s*)(lW + (b * 16 + m16) * 136 + kk + quad * 8);
                acc[b] = __builtin_amdgcn_mfma_f32_16x16x32_bf16(a, bb, acc[b], 0, 0, 0);
            }
        }
    }
    __syncthreads();
    float* lC = (float*)lX;
#pragma unroll
    for (int b = 0; b < 4; ++b)
#pragma unroll
        for (int r = 0; r < 4; ++r) {
            int rowt = w * 16 + quad * 4 + r;
            lC[rowt * 65 + b * 16 + m16] = acc[b][r];
        }
    __syncthreads();
#pragma unroll
    for (int i = 0; i < 2; ++i) {
        int base = i * 2048 + tid * 8;
        int r = base >> 6;
        int c = base & 63;
        int gr = row0 + r;
        if (gr < n_nodes) {
            float d = dinv[gr];
            const float* p = lC + r * 65 + c;
            unsigned p0 = (unsigned)f2bf(p[0] * d) | ((unsigned)f2bf(p[1] * d) << 16);
            unsigned p1 = (unsigned)f2bf(p[2] * d) | ((unsigned)f2bf(p[3] * d) << 16);
            unsigned p2 = (unsigned)f2bf(p[4] * d) | ((unsigned)f2bf(p[5] * d) << 16);
            unsigned p3 = (unsigned)f2bf(p[6] * d) | ((unsigned)f2bf(p[7] * d) << 16);
            *(uint4*)(s1 + (size_t)gr * 64 + c) = make_uint4(p0, p1, p2, p3);
        }
    }
}

// ---------------- fused layer1: degree-sorted gather + block MFMA GEMM2 ----
// Nodes processed in perm order (sorted by chunk count): the 8 nodes of a
// wave and the 32 of a block have ~equal degree, so the divergent chunk loop
// runs ~mean instead of ~max iterations (-27% chunk work).
__launch_bounds__(256)
__global__ void k_agg1g2(const unsigned short* __restrict__ sin, const int* __restrict__ row_start,
                         const int* __restrict__ csr, const float* __restrict__ dinv,
                         const unsigned short* __restrict__ Wt2, const float* __restrict__ b1,
                         const int* __restrict__ perm,
                         unsigned short* __restrict__ sout, int n_nodes) {
    __shared__ __align__(16) unsigned short lW[64 * 72];   // W2^T bf16 (9.2 KB)
    __shared__ __align__(16) unsigned short lA[32 * 72];   // A tile bf16 (4.6 KB)
    __shared__ __align__(16) float lC[32 * 65];            // epilogue (8.3 KB)
    const int tid  = threadIdx.x;
    const int lane = tid & 63;
    const int wave = tid >> 6;
    const int g = lane >> 3;     // node slot within wave (0..7)
    const int l = lane & 7;      // feature lane: floats 8l..8l+7
    const int row0 = blockIdx.x * 32;
    const int gid = row0 + wave * 8 + g;
    const bool valid = (gid < n_nodes);
    const int n = valid ? perm[gid] : 0;
    const char* sp = (const char*)sin;
    const int SENTB = n_nodes << 7;   // sentinel zero row (byte offset)

    // stage W2^T (bf16) while gather loads are in flight
#pragma unroll
    for (int i = 0; i < 2; ++i) {
        int idx = tid + i * 256;   // 0..511
        int nn = idx >> 3;
        int c8 = idx & 7;
        uint4 u = *(const uint4*)(Wt2 + (size_t)nn * 64 + c8 * 8);
        *(uint4*)(lW + nn * 72 + c8 * 8) = u;
    }

    int rs = 0, re = 0;
    if (valid) { rs = row_start[n]; re = row_start[n + 1]; }

    // init acc with the self row (sentinel for invalid slots)
    uint4 us = *(const uint4*)(sp + (size_t)(valid ? (n << 7) : SENTB) + l * 16);
    float acc0 = bflo(us.x), acc1 = bfhi(us.x);
    float acc2 = bflo(us.y), acc3 = bfhi(us.y);
    float acc4 = bflo(us.z), acc5 = bfhi(us.z);
    float acc6 = bflo(us.w), acc7 = bfhi(us.w);

    for (int base = rs; base < re; base += 16) {
        int p0 = base + l;
        int p1 = base + 8 + l;
        int a0 = (p0 < re) ? csr[p0] : SENTB;
        int a1 = (p1 < re) ? csr[p1] : SENTB;
#pragma unroll
        for (int j = 0; j < 8; ++j) {
            int ab = __shfl(a0, g * 8 + j, 64);
            uint4 u = *(const uint4*)(sp + (size_t)(unsigned)ab + l * 16);
            acc0 += bflo(u.x); acc1 += bfhi(u.x);
            acc2 += bflo(u.y); acc3 += bfhi(u.y);
            acc4 += bflo(u.z); acc5 += bfhi(u.z);
            acc6 += bflo(u.w); acc7 += bfhi(u.w);
        }
#pragma unroll
        for (int j = 0; j < 8; ++j) {
            int ab = __shfl(a1, g * 8 + j, 64);
            uint4 u = *(const uint4*)(sp + (size_t)(unsigned)ab + l * 16);
            acc0 += bflo(u.x); acc1 += bfhi(u.x);
            acc2 += bflo(u.y); acc3 += bfhi(u.y);
            acc4 += bflo(u.z); acc5 += bfhi(u.z);
            acc6 += bflo(u.w); acc7 += bfhi(u.w);
        }
    }
    // finalize: v = relu(d*acc + b1), pack bf16 into the A-tile
    {
        float d = valid ? dinv[n] : 0.f;
        const float4 bA = ((const float4*)b1)[2 * l];
        const float4 bB = ((const float4*)b1)[2 * l + 1];
        float t0 = d * acc0, t1 = d * acc1, t2 = d * acc2, t3 = d * acc3;
        float t4 = d * acc4, t5 = d * acc5, t6 = d * acc6, t7 = d * acc7;
        float v0 = fmaxf(t0 + bA.x, 0.f), v1 = fmaxf(t1 + bA.y, 0.f);
        float v2 = fmaxf(t2 + bA.z, 0.f), v3 = fmaxf(t3 + bA.w, 0.f);
        float v4 = fmaxf(t4 + bB.x, 0.f), v5 = fmaxf(t5 + bB.y, 0.f);
        float v6 = fmaxf(t6 + bB.z, 0.f), v7 = fmaxf(t7 + bB.w, 0.f);
        unsigned q0 = (unsigned)f2bf(v0) | ((unsigned)f2bf(v1) << 16);
        unsigned q1 = (unsigned)f2bf(v2) | ((unsigned)f2bf(v3) << 16);
        unsigned q2 = (unsigned)f2bf(v4) | ((unsigned)f2bf(v5) << 16);
        unsigned q3 = (unsigned)f2bf(v6) | ((unsigned)f2bf(v7) << 16);
        int r = wave * 8 + g;
        *(uint4*)(lA + r * 72 + l * 8) = make_uint4(q0, q1, q2, q3);
    }
    __syncthreads();
    // MFMA: M=32 (2 tiles) x N=64 (4 tiles) x K=64, 2 C-tiles per wave
    {
        const int m16  = lane & 15;
        const int quad = lane >> 4;
        const int mt  = wave >> 1;
        const int nt0 = (wave & 1) * 2;
        v4f c0 = (v4f){0.f, 0.f, 0.f, 0.f};
        v4f c1 = (v4f){0.f, 0.f, 0.f, 0.f};
#pragma unroll
        for (int kk = 0; kk < 64; kk += 32) {
            v8s a  = *(const v8s*)(lA + (mt * 16 + m16) * 72 + kk + quad * 8);
            v8s b0 = *(const v8s*)(lW + (nt0 * 16 + m16) * 72 + kk + quad * 8);
            v8s b1v = *(const v8s*)(lW + ((nt0 + 1) * 16 + m16) * 72 + kk + quad * 8);
            c0 = __builtin_amdgcn_mfma_f32_16x16x32_bf16(a, b0, c0, 0, 0, 0);
            c1 = __builtin_amdgcn_mfma_f32_16x16x32_bf16(a, b1v, c1, 0, 0, 0);
        }
#pragma unroll
        for (int r = 0; r < 4; ++r) {
            int rowt = mt * 16 + quad * 4 + r;
            lC[rowt * 65 + nt0 * 16 + m16]       = c0[r];
            lC[rowt * 65 + (nt0 + 1) * 16 + m16] = c1[r];
        }
    }
    __syncthreads();
    // epilogue: 32 rows x 64 cols, dinv scale, bf16 store to perm'd rows
    {
        int base = tid * 8;
        int r = base >> 6;
        int c = base & 63;
        int gid2 = row0 + r;
        if (gid2 < n_nodes) {
            int gr = perm[gid2];
            float d = dinv[gr];
            const float* p = lC + r * 65 + c;
            unsigned p0 = (unsigned)f2bf(p[0] * d) | ((unsigned)f2bf(p[1] * d) << 16);
            unsigned p1 = (unsigned)f2bf(p[2] * d) | ((unsigned)f2bf(p[3] * d) << 16);
            unsigned p2 = (unsigned)f2bf(p[4] * d) | ((unsigned)f2bf(p[5] * d) << 16);
            unsigned p3 = (unsigned)f2bf(p[6] * d) | ((unsigned)f2bf(p[7] * d) << 16);
            *(uint4*)(sout + (size_t)gr * 64 + c) = make_uint4(p0, p1, p2, p3);
        }
    }
}

// ---------------- layer2: degree-sorted gather + Wfc dot + pool ------------
__launch_bounds__(256)
__global__ void k_layer2pool(const unsigned short* __restrict__ sin, const int* __restrict__ row_start,
                             const int* __restrict__ csr, const float* __restrict__ b2,
                             const float* __restrict__ dinv, const float* __restrict__ Wfc,
                             const int* __restrict__ batch, const int* __restrict__ perm,
                             float* gsum, int* gcnt, int n_nodes) {
    __shared__ float lsum[256];
    __shared__ int   lcnt[256];
    const int tid = threadIdx.x;
    lsum[tid] = 0.f; lcnt[tid] = 0;
    __syncthreads();
    const int lane = tid & 63;
    const int wave = tid >> 6;
    const int g = lane >> 3;
    const int l = lane & 7;
    const int gid = (blockIdx.x * 4 + wave) * 8 + g;
    const bool valid = (gid < n_nodes);
    const int n = valid ? perm[gid] : 0;
    const char* sp = (const char*)sin;
    const int SENTB = n_nodes << 7;

    int rs = 0, re = 0;
    if (valid) { rs = row_start[n]; re = row_start[n + 1]; }

    uint4 us = *(const uint4*)(sp + (size_t)(valid ? (n << 7) : SENTB) + l * 16);
    float acc0 = bflo(us.x), acc1 = bfhi(us.x);
    float acc2 = bflo(us.y), acc3 = bfhi(us.y);
    float acc4 = bflo(us.z), acc5 = bfhi(us.z);
    float acc6 = bflo(us.w), acc7 = bfhi(us.w);

    for (int base = rs; base < re; base += 16) {
        int p0 = base + l;
        int p1 = base + 8 + l;
        int a0 = (p0 < re) ? csr[p0] : SENTB;
        int a1 = (p1 < re) ? csr[p1] : SENTB;
#pragma unroll
        for (int j = 0; j < 8; ++j) {
            int ab = __shfl(a0, g * 8 + j, 64);
            uint4 u = *(const uint4*)(sp + (size_t)(unsigned)ab + l * 16);
            acc0 += bflo(u.x); acc1 += bfhi(u.x);
            acc2 += bflo(u.y); acc3 += bfhi(u.y);
            acc4 += bflo(u.z); acc5 += bfhi(u.z);
            acc6 += bflo(u.w); acc7 += bfhi(u.w);
        }
#pragma unroll
        for (int j = 0; j < 8; ++j) {
            int ab = __shfl(a1, g * 8 + j, 64);
            uint4 u = *(const uint4*)(sp + (size_t)(unsigned)ab + l * 16);
            acc0 += bflo(u.x); acc1 += bfhi(u.x);
            acc2 += bflo(u.y); acc3 += bfhi(u.y);
            acc4 += bflo(u.z); acc5 += bfhi(u.z);
            acc6 += bflo(u.w); acc7 += bfhi(u.w);
        }
    }
    float d = dinv[n];
    const float4 bA  = ((const float4*)b2)[2 * l];
    const float4 bB  = ((const float4*)b2)[2 * l + 1];
    const float4 wA  = ((const float4*)Wfc)[2 * l];
    const float4 wB  = ((const float4*)Wfc)[2 * l + 1];
    float t = fmaxf(fmaf(d, acc0, bA.x), 0.f) * wA.x
            + fmaxf(fmaf(d, acc1, bA.y), 0.f) * wA.y
            + fmaxf(fmaf(d, acc2, bA.z), 0.f) * wA.z
            + fmaxf(fmaf(d, acc3, bA.w), 0.f) * wA.w
            + fmaxf(fmaf(d, acc4, bB.x), 0.f) * wB.x
            + fmaxf(fmaf(d, acc5, bB.y), 0.f) * wB.y
            + fmaxf(fmaf(d, acc6, bB.z), 0.f) * wB.z
            + fmaxf(fmaf(d, acc7, bB.w), 0.f) * wB.w;
    // 8-lane tree within the group (shared shuffle instrs across 8 groups)
#pragma unroll
    for (int off = 4; off; off >>= 1) t += __shfl_down(t, off, 8);
    if (l == 0 && valid) {
        int gr = batch[n];
        atomicAdd(&lsum[gr], t);
        atomicAdd(&lcnt[gr], 1);
    }
    __syncthreads();
    if (lcnt[tid]) {
        atomicAdd(&gsum[tid], lsum[tid]);
        atomicAdd(&gcnt[tid], lcnt[tid]);
    }
}

__global__ void k_out(const float* __restrict__ gsum, const int* __restrict__ gcnt,
                      const float* __restrict__ bfc, float* out) {
    int g = threadIdx.x;
    if (g < 256) {
        float c = (float)(gcnt[g] > 1 ? gcnt[g] : 1);
        out[g] = gsum[g] / c + bfc[0];
    }
}

// ---------------------------------------------------------------------------
extern "C" void kernel_launch(void* const* d_in, const int* in_sizes, int n_in,
                              void* d_out, int out_size, void* d_ws, size_t ws_size,
                              hipStream_t stream) {
    const float* x   = (const float*)d_in[0];
    const int*   ei  = (const int*)d_in[1];
    const int*   bat = (const int*)d_in[2];
    const float* W1  = (const float*)d_in[3];
    const float* b1  = (const float*)d_in[4];
    const float* W2  = (const float*)d_in[5];
    const float* b2  = (const float*)d_in[6];
    const float* Wfc = (const float*)d_in[7];
    const float* bfc = (const float*)d_in[8];
    float* out = (float*)d_out;

    const int n_nodes = in_sizes[2];
    const int n_edges = in_sizes[1] / 2;
    const int* src = ei;
    const int* dst = ei + n_edges;
    const int NBUCK = (n_nodes + 127) >> 7;

    char* w = (char*)d_ws;
    size_t off = 0;
    auto alloc = [&](size_t bytes) -> void* {
        void* p = w + off;
        off += (bytes + 255) & ~(size_t)255;
        return p;
    };
    float* dinv = (float*)alloc((size_t)n_nodes * sizeof(float));
    unsigned short* bufA = (unsigned short*)alloc(((size_t)n_nodes + 1) * HIDDEN * 2);
    unsigned short* bufB = (unsigned short*)alloc(((size_t)n_nodes + 1) * HIDDEN * 2);
    unsigned short* Wt   = (unsigned short*)alloc((size_t)HIDDEN * IN_DIM * 2);
    unsigned short* Wt2  = (unsigned short*)alloc((size_t)HIDDEN * HIDDEN * 2);
    float* gsum = (float*)alloc(256 * sizeof(float));
    int*   gcnt = (int*)  alloc(256 * sizeof(int));
    int*   cursor      = (int*)alloc((size_t)NB_MAX * sizeof(int));
    int*   bucket_base = (int*)alloc((size_t)NB_MAX * sizeof(int));
    int*   ghist       = (int*)alloc((size_t)DBINS * sizeof(int));
    int*   dcur        = (int*)alloc((size_t)DBINS * sizeof(int));
    int*   perm        = (int*)alloc((size_t)n_nodes * sizeof(int));
    unsigned* bucket_data = (unsigned*)alloc((size_t)NB_MAX * CAP * sizeof(unsigned));
    int* row_start = (int*)alloc(((size_t)n_nodes + 1) * sizeof(int));
    int* csr       = (int*)alloc(((size_t)n_edges + 64) * sizeof(int));
    (void)ws_size; (void)n_in; (void)out_size;

    hipLaunchKernelGGL(k_init, dim3(NB_MAX / 256), dim3(256), 0, stream,
                       cursor, gsum, gcnt, bufA, bufB, ghist, n_nodes);
    hipLaunchKernelGGL(k_bin, dim3((n_edges + 4095) / 4096), dim3(256), 0, stream,
                       src, dst, cursor, bucket_data, n_edges);
    hipLaunchKernelGGL(k_bexc, dim3(1), dim3(256), 0, stream,
                       cursor, bucket_base, row_start, n_nodes, NBUCK);
    hipLaunchKernelGGL(k_csr, dim3(NBUCK), dim3(256), 0, stream,
                       bucket_data, cursor, bucket_base, row_start, csr, dinv, ghist, n_nodes);
    hipLaunchKernelGGL(k_cscan, dim3(1), dim3(256), 0, stream, ghist, dcur);
    hipLaunchKernelGGL(k_cplace, dim3((n_nodes + 4095) / 4096), dim3(256), 0, stream,
                       row_start, dcur, perm, n_nodes);
    hipLaunchKernelGGL(k_prep, dim3((HIDDEN * IN_DIM + HIDDEN * HIDDEN) / 256), dim3(256), 0, stream,
                       W1, W2, Wt, Wt2);
    hipLaunchKernelGGL(k_gemm1m, dim3((n_nodes + 63) / 64), dim3(256), 0, stream,
                       x, Wt, dinv, bufA, n_nodes);
    hipLaunchKernelGGL(k_agg1g2, dim3((n_nodes + 31) / 32), dim3(256), 0, stream,
                       bufA, row_start, csr, dinv, Wt2, b1, perm, bufB, n_nodes);
    hipLaunchKernelGGL(k_layer2pool, dim3((n_nodes + 31) / 32), dim3(256), 0, stream,
                       bufB, row_start, csr, b2, dinv, Wfc, bat, perm, gsum, gcnt, n_nodes);
    hipLaunchKernelGGL(k_out, dim3(1), dim3(256), 0, stream, gsum, gcnt, bfc, out);
}

// Round 10
// 409.817 us; speedup vs baseline: 1.0602x; 1.0602x over previous
//
#include <hip/hip_runtime.h>

#define HIDDEN 64
#define IN_DIM 512
#define CAP 4096      // bucket capacity (mean load ~2046 for E=1.6M over 782 buckets; 45 sigma headroom)
#define NB_MAX 1024   // max buckets (n_nodes <= 131072)

typedef short v8s __attribute__((ext_vector_type(8)));
typedef float v4f __attribute__((ext_vector_type(4)));

static __device__ __forceinline__ unsigned short f2bf(float f) {
    unsigned int u = __float_as_uint(f);
    u = (u + 0x7FFF + ((u >> 16) & 1)) >> 16;   // RNE
    return (unsigned short)u;
}
static __device__ __forceinline__ float bf2f(unsigned short u) {
    return __uint_as_float(((unsigned int)u) << 16);
}
static __device__ __forceinline__ float bflo(unsigned u) { return __uint_as_float(u << 16); }
static __device__ __forceinline__ float bfhi(unsigned u) { return __uint_as_float(u & 0xffff0000u); }

// ---------------- init: zero cursors + pool accumulators + sentinel rows ---
__global__ void k_init(int* cursor, float* gsum, int* gcnt,
                       unsigned short* bufA, unsigned short* bufB, int n_nodes) {
    int i = blockIdx.x * 256 + threadIdx.x;
    if (i < NB_MAX) cursor[i] = 0;
    if (i < 256) { gsum[i] = 0.f; gcnt[i] = 0; }
    if (i < 64) {
        bufA[(size_t)n_nodes * 64 + i] = 0;
        bufB[(size_t)n_nodes * 64 + i] = 0;
    }
}

// ---------------- bin edges by dst>>7 into fixed-stride buckets ------------
__launch_bounds__(256)
__global__ void k_bin(const int* __restrict__ src, const int* __restrict__ dst,
                      int* cursor, unsigned* __restrict__ bucket_data, int n_edges) {
    __shared__ unsigned words[4096];          // 16 KB
    __shared__ unsigned short binsh[4096];    // 8 KB
    __shared__ int hist[NB_MAX];              // 4 KB
    __shared__ int base[NB_MAX];              // 4 KB
    const int tid = threadIdx.x;
    const int e0 = blockIdx.x * 4096;
    for (int i = tid; i < NB_MAX; i += 256) hist[i] = 0;
    __syncthreads();
    for (int i = tid; i < 4096; i += 256) {
        int e = e0 + i;
        if (e < n_edges) {
            int d = dst[e], s = src[e];
            words[i] = ((unsigned)s << 7) | (unsigned)(d & 127);
            int b = d >> 7;
            binsh[i] = (unsigned short)b;
            atomicAdd(&hist[b], 1);
        } else binsh[i] = 0xFFFFu;
    }
    __syncthreads();
    for (int b = tid; b < NB_MAX; b += 256) {
        int c = hist[b];
        base[b] = c ? atomicAdd(&cursor[b], c) : 0;
        hist[b] = 0;
    }
    __syncthreads();
    for (int i = tid; i < 4096; i += 256) {
        unsigned short b = binsh[i];
        if (b != 0xFFFFu) {
            int slot = atomicAdd(&hist[b], 1);
            int p = base[b] + slot;
            if (p < CAP) bucket_data[(size_t)b * CAP + p] = words[i];
        }
    }
}

// ---------------- exclusive scan of bucket counts -> bucket_base -----------
__launch_bounds__(256)
__global__ void k_bexc(const int* __restrict__ cursor, int* __restrict__ bucket_base,
                       int* __restrict__ row_start, int n_nodes, int nbuck) {
    __shared__ int wsum[4];
    const int t = threadIdx.x, lane = t & 63, w = t >> 6;
    int v[4], s = 0;
#pragma unroll
    for (int k = 0; k < 4; ++k) {
        int i = t * 4 + k;
        int c = (i < nbuck) ? cursor[i] : 0;
        if (c > CAP) c = CAP;
        v[k] = s; s += c;
    }
    int inc = s;
#pragma unroll
    for (int off = 1; off < 64; off <<= 1) {
        int u = __shfl_up(inc, off, 64);
        if (lane >= off) inc += u;
    }
    if (lane == 63) wsum[w] = inc;
    __syncthreads();
    int cross = 0;
    for (int i = 0; i < w; ++i) cross += wsum[i];
    int b0 = cross + inc - s;
#pragma unroll
    for (int k = 0; k < 4; ++k) {
        int i = t * 4 + k;
        if (i < NB_MAX) bucket_base[i] = b0 + v[k];
    }
    if (t == 255) row_start[n_nodes] = cross + inc;   // total kept edges
}

// ---------------- per-bucket CSR build (coalesced, local LDS) --------------
// csr entries are PRE-SCALED byte offsets (src*128) for the gather kernels.
__launch_bounds__(256)
__global__ void k_csr(const unsigned* __restrict__ bucket_data, const int* __restrict__ cursor,
                      const int* __restrict__ bucket_base,
                      int* __restrict__ row_start, int* __restrict__ csr,
                      float* __restrict__ dinv, int n_nodes) {
    __shared__ unsigned words[CAP];   // 16 KB
    __shared__ int cnt[128];
    __shared__ int loff[128];
    __shared__ int cur[128];
    __shared__ int w0sum;
    const int tid = threadIdx.x, bin = blockIdx.x, n0 = bin << 7;
    int c = cursor[bin]; if (c > CAP) c = CAP;
    const unsigned* bd = bucket_data + (size_t)bin * CAP;
    for (int i = tid; i < c; i += 256) words[i] = bd[i];
    if (tid < 128) { cnt[tid] = 0; cur[tid] = 0; }
    __syncthreads();
    for (int i = tid; i < c; i += 256) atomicAdd(&cnt[words[i] & 127], 1);
    __syncthreads();
    int val = 0, inc = 0;
    if (tid < 128) {
        const int lane = tid & 63;
        val = cnt[tid];
        inc = val;
#pragma unroll
        for (int off = 1; off < 64; off <<= 1) {
            int u = __shfl_up(inc, off, 64);
            if (lane >= off) inc += u;
        }
        if (tid == 63) w0sum = inc;
    }
    __syncthreads();
    if (tid < 128) {
        int excl = inc - val + ((tid >= 64) ? w0sum : 0);
        loff[tid] = excl;
        int n = n0 + tid;
        if (n < n_nodes) {
            row_start[n] = bucket_base[bin] + excl;
            dinv[n] = rsqrtf((float)(val + 1));   // +1 self loop
        }
    }
    __syncthreads();
    const int gbase = bucket_base[bin];
    for (int i = tid; i < c; i += 256) {
        unsigned wd = words[i];
        int d = wd & 127;
        int slot = atomicAdd(&cur[d], 1);
        csr[gbase + loff[d] + slot] = (int)(wd & 0xFFFFFF80u);  // src*128 byte offset
    }
}

// ---------------- W1,W2 -> bf16 transposed Wt [64][512], Wt2 [64][64] ------
__global__ void k_prep(const float* __restrict__ W1, const float* __restrict__ W2,
                       unsigned short* __restrict__ Wt, unsigned short* __restrict__ Wt2) {
    int idx = blockIdx.x * 256 + threadIdx.x;
    if (idx < HIDDEN * IN_DIM) {
        int n = idx >> 9, k = idx & 511;
        Wt[(size_t)n * 512 + k] = f2bf(W1[(size_t)k * 64 + n]);
    } else {
        int j = idx - HIDDEN * IN_DIM;   // 0..4095
        int n = j >> 6, k = j & 63;
        Wt2[(size_t)n * 64 + k] = f2bf(W2[(size_t)k * 64 + n]);
    }
}

// ---------------- GEMM1 (MFMA bf16): s1 = bf16(dinv .* (x @ W1)) -----------
__launch_bounds__(256)
__global__ void k_gemm1m(const float* __restrict__ x, const unsigned short* __restrict__ Wt,
                         const float* __restrict__ dinv, unsigned short* __restrict__ s1,
                         int n_nodes) {
    __shared__ __align__(16) unsigned short lX[64 * 136];
    __shared__ __align__(16) unsigned short lW[64 * 136];
    const int tid  = threadIdx.x;
    const int lane = tid & 63;
    const int w    = tid >> 6;
    const int quad = lane >> 4;
    const int m16  = lane & 15;
    const int row0 = blockIdx.x * 64;

    v4f acc[4];
#pragma unroll
    for (int b = 0; b < 4; ++b) acc[b] = (v4f){0.f, 0.f, 0.f, 0.f};

    for (int kc = 0; kc < IN_DIM; kc += 128) {
        __syncthreads();
#pragma unroll
        for (int i = 0; i < 8; ++i) {
            int fidx = tid + i * 256;
            int r  = fidx >> 5;
            int c4 = fidx & 31;
            int gr = row0 + r;
            float4 v = make_float4(0.f, 0.f, 0.f, 0.f);
            if (gr < n_nodes) v = ((const float4*)(x + (size_t)gr * IN_DIM + kc))[c4];
            ushort4 u = make_ushort4(f2bf(v.x), f2bf(v.y), f2bf(v.z), f2bf(v.w));
            *(ushort4*)(lX + r * 136 + c4 * 4) = u;
        }
#pragma unroll
        for (int i = 0; i < 4; ++i) {
            int idx = tid + i * 256;
            int n  = idx >> 4;
            int c8 = idx & 15;
            uint4 u = *(const uint4*)(Wt + (size_t)n * 512 + kc + c8 * 8);
            *(uint4*)(lW + n * 136 + c8 * 8) = u;
        }
        __syncthreads();
#pragma unroll
        for (int kk = 0; kk < 128; kk += 32) {
            v8s a = *(const v8s*)(lX + (w * 16 + m16) * 136 + kk + quad * 8);
#pragma unroll
            for (int b = 0; b < 4; ++b) {
                v8s bb = *(const v8s*)(lW + (b * 16 + m16) * 136 + kk + quad * 8);
                acc[b] = __builtin_amdgcn_mfma_f32_16x16x32_bf16(a, bb, acc[b], 0, 0, 0);
            }
        }
    }
    __syncthreads();
    float* lC = (float*)lX;
#pragma unroll
    for (int b = 0; b < 4; ++b)
#pragma unroll
        for (int r = 0; r < 4; ++r) {
            int rowt = w * 16 + quad * 4 + r;
            lC[rowt * 65 + b * 16 + m16] = acc[b][r];
        }
    __syncthreads();
#pragma unroll
    for (int i = 0; i < 2; ++i) {
        int base = i * 2048 + tid * 8;
        int r = base >> 6;
        int c = base & 63;
        int gr = row0 + r;
        if (gr < n_nodes) {
            float d = dinv[gr];
            const float* p = lC + r * 65 + c;
            unsigned p0 = (unsigned)f2bf(p[0] * d) | ((unsigned)f2bf(p[1] * d) << 16);
            unsigned p1 = (unsigned)f2bf(p[2] * d) | ((unsigned)f2bf(p[3] * d) << 16);
            unsigned p2 = (unsigned)f2bf(p[4] * d) | ((unsigned)f2bf(p[5] * d) << 16);
            unsigned p3 = (unsigned)f2bf(p[6] * d) | ((unsigned)f2bf(p[7] * d) << 16);
            *(uint4*)(s1 + (size_t)gr * 64 + c) = make_uint4(p0, p1, p2, p3);
        }
    }
}

// ---------------- fused layer1: 8-lane-group gather + block MFMA GEMM2 -----
// Round-8 structure (natural node order: coalesced self/csr/output traffic)
// + chunk-ahead csr prefetch: chunk k+1's two index loads issue before
// chunk k's 16 gathers consume a0/a1, hiding the csr-load latency that the
// first __shfl of each chunk otherwise waits on.
__launch_bounds__(256)
__global__ void k_agg1g2(const unsigned short* __restrict__ sin, const int* __restrict__ row_start,
                         const int* __restrict__ csr, const float* __restrict__ dinv,
                         const unsigned short* __restrict__ Wt2, const float* __restrict__ b1,
                         unsigned short* __restrict__ sout, int n_nodes) {
    __shared__ __align__(16) unsigned short lW[64 * 72];   // W2^T bf16 (9.2 KB)
    __shared__ __align__(16) unsigned short lA[32 * 72];   // A tile bf16 (4.6 KB)
    __shared__ __align__(16) float lC[32 * 65];            // epilogue (8.3 KB)
    const int tid  = threadIdx.x;
    const int lane = tid & 63;
    const int wave = tid >> 6;
    const int g = lane >> 3;     // node slot within wave (0..7)
    const int l = lane & 7;      // feature lane: floats 8l..8l+7
    const int row0 = blockIdx.x * 32;
    const int n = row0 + wave * 8 + g;
    const bool valid = (n < n_nodes);
    const char* sp = (const char*)sin;
    const int SENTB = n_nodes << 7;   // sentinel zero row (byte offset)

    // stage W2^T (bf16) while gather loads are in flight
#pragma unroll
    for (int i = 0; i < 2; ++i) {
        int idx = tid + i * 256;   // 0..511
        int nn = idx >> 3;
        int c8 = idx & 7;
        uint4 u = *(const uint4*)(Wt2 + (size_t)nn * 64 + c8 * 8);
        *(uint4*)(lW + nn * 72 + c8 * 8) = u;
    }

    int rs = 0, re = 0;
    if (valid) { rs = row_start[n]; re = row_start[n + 1]; }

    // init acc with the self row (sentinel for invalid slots)
    uint4 us = *(const uint4*)(sp + (size_t)(valid ? (n << 7) : SENTB) + l * 16);
    float acc0 = bflo(us.x), acc1 = bfhi(us.x);
    float acc2 = bflo(us.y), acc3 = bfhi(us.y);
    float acc4 = bflo(us.z), acc5 = bfhi(us.z);
    float acc6 = bflo(us.w), acc7 = bfhi(us.w);

    // prime chunk 0 indices
    int a0 = SENTB, a1 = SENTB;
    if (rs < re) {
        a0 = (rs + l < re) ? csr[rs + l] : SENTB;
        a1 = (rs + 8 + l < re) ? csr[rs + 8 + l] : SENTB;
    }
    for (int base = rs; base < re; base += 16) {
        // prefetch next chunk's indices before consuming this chunk's
        int nb = base + 16;
        int na0 = SENTB, na1 = SENTB;
        if (nb < re) {
            na0 = (nb + l < re) ? csr[nb + l] : SENTB;
            na1 = (nb + 8 + l < re) ? csr[nb + 8 + l] : SENTB;
        }
#pragma unroll
        for (int j = 0; j < 8; ++j) {
            int ab = __shfl(a0, g * 8 + j, 64);
            uint4 u = *(const uint4*)(sp + (size_t)(unsigned)ab + l * 16);
            acc0 += bflo(u.x); acc1 += bfhi(u.x);
            acc2 += bflo(u.y); acc3 += bfhi(u.y);
            acc4 += bflo(u.z); acc5 += bfhi(u.z);
            acc6 += bflo(u.w); acc7 += bfhi(u.w);
        }
#pragma unroll
        for (int j = 0; j < 8; ++j) {
            int ab = __shfl(a1, g * 8 + j, 64);
            uint4 u = *(const uint4*)(sp + (size_t)(unsigned)ab + l * 16);
            acc0 += bflo(u.x); acc1 += bfhi(u.x);
            acc2 += bflo(u.y); acc3 += bfhi(u.y);
            acc4 += bflo(u.z); acc5 += bfhi(u.z);
            acc6 += bflo(u.w); acc7 += bfhi(u.w);
        }
        a0 = na0; a1 = na1;
    }
    // finalize: v = relu(d*acc + b1), pack bf16 into the A-tile
    {
        float d = valid ? dinv[n] : 0.f;
        const float4 bA = ((const float4*)b1)[2 * l];
        const float4 bB = ((const float4*)b1)[2 * l + 1];
        float t0 = d * acc0, t1 = d * acc1, t2 = d * acc2, t3 = d * acc3;
        float t4 = d * acc4, t5 = d * acc5, t6 = d * acc6, t7 = d * acc7;
        float v0 = fmaxf(t0 + bA.x, 0.f), v1 = fmaxf(t1 + bA.y, 0.f);
        float v2 = fmaxf(t2 + bA.z, 0.f), v3 = fmaxf(t3 + bA.w, 0.f);
        float v4 = fmaxf(t4 + bB.x, 0.f), v5 = fmaxf(t5 + bB.y, 0.f);
        float v6 = fmaxf(t6 + bB.z, 0.f), v7 = fmaxf(t7 + bB.w, 0.f);
        unsigned q0 = (unsigned)f2bf(v0) | ((unsigned)f2bf(v1) << 16);
        unsigned q1 = (unsigned)f2bf(v2) | ((unsigned)f2bf(v3) << 16);
        unsigned q2 = (unsigned)f2bf(v4) | ((unsigned)f2bf(v5) << 16);
        unsigned q3 = (unsigned)f2bf(v6) | ((unsigned)f2bf(v7) << 16);
        int r = wave * 8 + g;
        *(uint4*)(lA + r * 72 + l * 8) = make_uint4(q0, q1, q2, q3);
    }
    __syncthreads();
    // MFMA: M=32 (2 tiles) x N=64 (4 tiles) x K=64, 2 C-tiles per wave
    {
        const int m16  = lane & 15;
        const int quad = lane >> 4;
        const int mt  = wave >> 1;
        const int nt0 = (wave & 1) * 2;
        v4f c0 = (v4f){0.f, 0.f, 0.f, 0.f};
        v4f c1 = (v4f){0.f, 0.f, 0.f, 0.f};
#pragma unroll
        for (int kk = 0; kk < 64; kk += 32) {
            v8s a  = *(const v8s*)(lA + (mt * 16 + m16) * 72 + kk + quad * 8);
            v8s b0 = *(const v8s*)(lW + (nt0 * 16 + m16) * 72 + kk + quad * 8);
            v8s b1v = *(const v8s*)(lW + ((nt0 + 1) * 16 + m16) * 72 + kk + quad * 8);
            c0 = __builtin_amdgcn_mfma_f32_16x16x32_bf16(a, b0, c0, 0, 0, 0);
            c1 = __builtin_amdgcn_mfma_f32_16x16x32_bf16(a, b1v, c1, 0, 0, 0);
        }
#pragma unroll
        for (int r = 0; r < 4; ++r) {
            int rowt = mt * 16 + quad * 4 + r;
            lC[rowt * 65 + nt0 * 16 + m16]       = c0[r];
            lC[rowt * 65 + (nt0 + 1) * 16 + m16] = c1[r];
        }
    }
    __syncthreads();
    // coalesced epilogue: 32 rows x 64 cols, dinv scale, bf16 store
    {
        int base = tid * 8;
        int r = base >> 6;
        int c = base & 63;
        int gr = row0 + r;
        if (gr < n_nodes) {
            float d = dinv[gr];
            const float* p = lC + r * 65 + c;
            unsigned p0 = (unsigned)f2bf(p[0] * d) | ((unsigned)f2bf(p[1] * d) << 16);
            unsigned p1 = (unsigned)f2bf(p[2] * d) | ((unsigned)f2bf(p[3] * d) << 16);
            unsigned p2 = (unsigned)f2bf(p[4] * d) | ((unsigned)f2bf(p[5] * d) << 16);
            unsigned p3 = (unsigned)f2bf(p[6] * d) | ((unsigned)f2bf(p[7] * d) << 16);
            *(uint4*)(sout + (size_t)gr * 64 + c) = make_uint4(p0, p1, p2, p3);
        }
    }
}

// ---------------- layer2: 8-lane-group gather + Wfc dot + pool -------------
__launch_bounds__(256)
__global__ void k_layer2pool(const unsigned short* __restrict__ sin, const int* __restrict__ row_start,
                             const int* __restrict__ csr, const float* __restrict__ b2,
                             const float* __restrict__ dinv, const float* __restrict__ Wfc,
                             const int* __restrict__ batch,
                             float* gsum, int* gcnt, int n_nodes) {
    __shared__ float lsum[256];
    __shared__ int   lcnt[256];
    const int tid = threadIdx.x;
    lsum[tid] = 0.f; lcnt[tid] = 0;
    __syncthreads();
    const int lane = tid & 63;
    const int wave = tid >> 6;
    const int g = lane >> 3;
    const int l = lane & 7;
    const int n = (blockIdx.x * 4 + wave) * 8 + g;
    const bool valid = (n < n_nodes);
    const char* sp = (const char*)sin;
    const int SENTB = n_nodes << 7;

    int rs = 0, re = 0;
    if (valid) { rs = row_start[n]; re = row_start[n + 1]; }

    uint4 us = *(const uint4*)(sp + (size_t)(valid ? (n << 7) : SENTB) + l * 16);
    float acc0 = bflo(us.x), acc1 = bfhi(us.x);
    float acc2 = bflo(us.y), acc3 = bfhi(us.y);
    float acc4 = bflo(us.z), acc5 = bfhi(us.z);
    float acc6 = bflo(us.w), acc7 = bfhi(us.w);

    int a0 = SENTB, a1 = SENTB;
    if (rs < re) {
        a0 = (rs + l < re) ? csr[rs + l] : SENTB;
        a1 = (rs + 8 + l < re) ? csr[rs + 8 + l] : SENTB;
    }
    for (int base = rs; base < re; base += 16) {
        int nb = base + 16;
        int na0 = SENTB, na1 = SENTB;
        if (nb < re) {
            na0 = (nb + l < re) ? csr[nb + l] : SENTB;
            na1 = (nb + 8 + l < re) ? csr[nb + 8 + l] : SENTB;
        }
#pragma unroll
        for (int j = 0; j < 8; ++j) {
            int ab = __shfl(a0, g * 8 + j, 64);
            uint4 u = *(const uint4*)(sp + (size_t)(unsigned)ab + l * 16);
            acc0 += bflo(u.x); acc1 += bfhi(u.x);
            acc2 += bflo(u.y); acc3 += bfhi(u.y);
            acc4 += bflo(u.z); acc5 += bfhi(u.z);
            acc6 += bflo(u.w); acc7 += bfhi(u.w);
        }
#pragma unroll
        for (int j = 0; j < 8; ++j) {
            int ab = __shfl(a1, g * 8 + j, 64);
            uint4 u = *(const uint4*)(sp + (size_t)(unsigned)ab + l * 16);
            acc0 += bflo(u.x); acc1 += bfhi(u.x);
            acc2 += bflo(u.y); acc3 += bfhi(u.y);
            acc4 += bflo(u.z); acc5 += bfhi(u.z);
            acc6 += bflo(u.w); acc7 += bfhi(u.w);
        }
        a0 = na0; a1 = na1;
    }
    float d = dinv[valid ? n : 0];
    const float4 bA  = ((const float4*)b2)[2 * l];
    const float4 bB  = ((const float4*)b2)[2 * l + 1];
    const float4 wA  = ((const float4*)Wfc)[2 * l];
    const float4 wB  = ((const float4*)Wfc)[2 * l + 1];
    float t = fmaxf(fmaf(d, acc0, bA.x), 0.f) * wA.x
            + fmaxf(fmaf(d, acc1, bA.y), 0.f) * wA.y
            + fmaxf(fmaf(d, acc2, bA.z), 0.f) * wA.z
            + fmaxf(fmaf(d, acc3, bA.w), 0.f) * wA.w
            + fmaxf(fmaf(d, acc4, bB.x), 0.f) * wB.x
            + fmaxf(fmaf(d, acc5, bB.y), 0.f) * wB.y
            + fmaxf(fmaf(d, acc6, bB.z), 0.f) * wB.z
            + fmaxf(fmaf(d, acc7, bB.w), 0.f) * wB.w;
    // 8-lane tree within the group (shared shuffle instrs across 8 groups)
#pragma unroll
    for (int off = 4; off; off >>= 1) t += __shfl_down(t, off, 8);
    if (l == 0 && valid) {
        int gr = batch[n];
        atomicAdd(&lsum[gr], t);
        atomicAdd(&lcnt[gr], 1);
    }
    __syncthreads();
    if (lcnt[tid]) {
        atomicAdd(&gsum[tid], lsum[tid]);
        atomicAdd(&gcnt[tid], lcnt[tid]);
    }
}

__global__ void k_out(const float* __restrict__ gsum, const int* __restrict__ gcnt,
                      const float* __restrict__ bfc, float* out) {
    int g = threadIdx.x;
    if (g < 256) {
        float c = (float)(gcnt[g] > 1 ? gcnt[g] : 1);
        out[g] = gsum[g] / c + bfc[0];
    }
}

// ---------------------------------------------------------------------------
extern "C" void kernel_launch(void* const* d_in, const int* in_sizes, int n_in,
                              void* d_out, int out_size, void* d_ws, size_t ws_size,
                              hipStream_t stream) {
    const float* x   = (const float*)d_in[0];
    const int*   ei  = (const int*)d_in[1];
    const int*   bat = (const int*)d_in[2];
    const float* W1  = (const float*)d_in[3];
    const float* b1  = (const float*)d_in[4];
    const float* W2  = (const float*)d_in[5];
    const float* b2  = (const float*)d_in[6];
    const float* Wfc = (const float*)d_in[7];
    const float* bfc = (const float*)d_in[8];
    float* out = (float*)d_out;

    const int n_nodes = in_sizes[2];
    const int n_edges = in_sizes[1] / 2;
    const int* src = ei;
    const int* dst = ei + n_edges;
    const int NBUCK = (n_nodes + 127) >> 7;

    char* w = (char*)d_ws;
    size_t off = 0;
    auto alloc = [&](size_t bytes) -> void* {
        void* p = w + off;
        off += (bytes + 255) & ~(size_t)255;
        return p;
    };
    float* dinv = (float*)alloc((size_t)n_nodes * sizeof(float));
    unsigned short* bufA = (unsigned short*)alloc(((size_t)n_nodes + 1) * HIDDEN * 2);
    unsigned short* bufB = (unsigned short*)alloc(((size_t)n_nodes + 1) * HIDDEN * 2);
    unsigned short* Wt   = (unsigned short*)alloc((size_t)HIDDEN * IN_DIM * 2);
    unsigned short* Wt2  = (unsigned short*)alloc((size_t)HIDDEN * HIDDEN * 2);
    float* gsum = (float*)alloc(256 * sizeof(float));
    int*   gcnt = (int*)  alloc(256 * sizeof(int));
    int*   cursor      = (int*)alloc((size_t)NB_MAX * sizeof(int));
    int*   bucket_base = (int*)alloc((size_t)NB_MAX * sizeof(int));
    unsigned* bucket_data = (unsigned*)alloc((size_t)NB_MAX * CAP * sizeof(unsigned));
    int* row_start = (int*)alloc(((size_t)n_nodes + 1) * sizeof(int));
    int* csr       = (int*)alloc(((size_t)n_edges + 64) * sizeof(int));
    (void)ws_size; (void)n_in; (void)out_size;

    hipLaunchKernelGGL(k_init, dim3(NB_MAX / 256), dim3(256), 0, stream,
                       cursor, gsum, gcnt, bufA, bufB, n_nodes);
    hipLaunchKernelGGL(k_bin, dim3((n_edges + 4095) / 4096), dim3(256), 0, stream,
                       src, dst, cursor, bucket_data, n_edges);
    hipLaunchKernelGGL(k_bexc, dim3(1), dim3(256), 0, stream,
                       cursor, bucket_base, row_start, n_nodes, NBUCK);
    hipLaunchKernelGGL(k_csr, dim3(NBUCK), dim3(256), 0, stream,
                       bucket_data, cursor, bucket_base, row_start, csr, dinv, n_nodes);
    hipLaunchKernelGGL(k_prep, dim3((HIDDEN * IN_DIM + HIDDEN * HIDDEN) / 256), dim3(256), 0, stream,
                       W1, W2, Wt, Wt2);
    hipLaunchKernelGGL(k_gemm1m, dim3((n_nodes + 63) / 64), dim3(256), 0, stream,
                       x, Wt, dinv, bufA, n_nodes);
    hipLaunchKernelGGL(k_agg1g2, dim3((n_nodes + 31) / 32), dim3(256), 0, stream,
                       bufA, row_start, csr, dinv, Wt2, b1, bufB, n_nodes);
    hipLaunchKernelGGL(k_layer2pool, dim3((n_nodes + 31) / 32), dim3(256), 0, stream,
                       bufB, row_start, csr, b2, dinv, Wfc, bat, gsum, gcnt, n_nodes);
    hipLaunchKernelGGL(k_out, dim3(1), dim3(256), 0, stream, gsum, gcnt, bfc, out);
}